// Round 10
// baseline (227.770 us; speedup 1.0000x reference)
//
#include <hip/hip_runtime.h>

// ROI-Align (crop_and_resize pad_border=True, 2x res + 2x2 avg pool) for
// fmap [1,200,304,256] f32, rois [N,4] f32, stride=16, out [N, 256*49] f32
// (NCHW-flattened). Symmetric pad of 1 == clamp(idx-1, 0, dim-1).
//
// R6 profile: dur 89us, FETCH 40MB (sort+swizzle worked), VALUBusy 31%,
// Occ 22% (LDS 51KB -> 3 blk/CU), LDS_BANK_CONFLICT 2.85M (8-way on
// compute-phase pool stores).
// R7: (a) two-phase pool (25+24 cells) -> LDS ~36KB -> 4 blk/CU;
//     (b) per-(cell,sample) weight/offset LDS tables (computed once, not
//         per-lane) -> ~35% less VALU in hot loop;
//     (c) pool column swizzle col' = c + (c>>5), row stride 289 (==1 mod 32)
//         -> conflict-free stores AND transpose reads.

#define HH 200
#define WW 304
#define CC 256
#define HP (HH + 2)
#define WP (WW + 2)
#define PS 14            // sample grid (2x resolution)
#define NCELL 49         // 7x7 pooled cells
#define PROWS 25         // pool rows per phase (25 then 24)
#define PSTRIDE 289      // row stride: >= 263 cols, == 1 mod 32
#define NBUCKET 256      // 16x16 morton tiles

// ---------- one-block counting sort: perm[sorted_pos] = roi_idx ----------
__global__ __launch_bounds__(256) void roi_sort_kernel(
    const float* __restrict__ rois,
    const int*   __restrict__ stride_p,
    int n, int* __restrict__ perm)
{
    __shared__ int hist[NBUCKET];
    __shared__ int scan[NBUCKET];
    __shared__ int offs[NBUCKET];
    const int t = threadIdx.x;
    hist[t] = 0;
    __syncthreads();

    const float inv = 1.0f / (float)stride_p[0];
    auto key_of = [&](int i) -> int {
        const float cx = 0.5f * (rois[4 * i + 0] + rois[4 * i + 2]) * inv;
        const float cy = 0.5f * (rois[4 * i + 1] + rois[4 * i + 3]) * inv;
        int tx = (int)(cx * (16.0f / (float)WW));
        int ty = (int)(cy * (16.0f / (float)HH));
        tx = min(max(tx, 0), 15);
        ty = min(max(ty, 0), 15);
        int k = 0;
#pragma unroll
        for (int b = 0; b < 4; ++b)
            k |= (((tx >> b) & 1) << (2 * b)) | (((ty >> b) & 1) << (2 * b + 1));
        return k;
    };

    for (int i = t; i < n; i += 256) atomicAdd(&hist[key_of(i)], 1);
    __syncthreads();

    scan[t] = hist[t];
    __syncthreads();
    for (int d = 1; d < NBUCKET; d <<= 1) {
        const int x = (t >= d) ? scan[t - d] : 0;
        __syncthreads();
        scan[t] += x;
        __syncthreads();
    }
    offs[t] = scan[t] - hist[t];   // exclusive
    __syncthreads();

    for (int i = t; i < n; i += 256) {
        const int pos = atomicAdd(&offs[key_of(i)], 1);
        perm[pos] = i;
    }
}

// ---------- main kernel ----------
__global__ __launch_bounds__(256, 4) void roi_align_kernel(
    const float* __restrict__ fmap,
    const float* __restrict__ rois,
    const int*   __restrict__ stride_p,
    const int*   __restrict__ perm,
    int nwg,
    float*       __restrict__ out)
{
    __shared__ float pool[PROWS * PSTRIDE];          // 28.9 KB
    __shared__ float wtab[NCELL * 16];               // 3.1 KB: [s][q][4] weights
    __shared__ int   otab[NCELL * 16];               // 3.1 KB: [s][q][4] f4-offsets
    __shared__ int   yo0[PS], yo1[PS], xo0[PS], xo1[PS];
    __shared__ float lyv[PS], vyv[PS], lxv[PS], vxv[PS];

    const int t = threadIdx.x;

    // bijective XCD-chunk swizzle: XCD k gets a contiguous sorted range
    const int bid = blockIdx.x;
    const int q8 = nwg >> 3, rem = nwg & 7;
    const int xcd = bid & 7, idx8 = bid >> 3;
    const int swz = (xcd < rem ? xcd * (q8 + 1) : rem * (q8 + 1) + (xcd - rem) * q8) + idx8;
    const int r = perm[swz];

    // ---- pass 1: separable index/weight tables (threads 0..27) ----
    if (t < 2 * PS) {
        const bool isx = (t >= PS);
        const int  i   = isx ? (t - PS) : t;
        const float inv = 1.0f / (float)stride_p[0];
        const float a0 = rois[4 * r + (isx ? 0 : 1)] * inv + 1.0f;
        const float a1 = rois[4 * r + (isx ? 2 : 3)] * inv + 1.0f;
        const float sc = (a1 - a0) / (float)PS;
        const float coord = a0 + sc * ((float)i + 0.5f) - 0.5f;
        const int size = isx ? WP : HP;

        const float f0   = floorf(coord);
        const float frac = coord - f0;
        int i0 = (int)f0;
        i0 = min(max(i0, 0), size - 1);
        const int i1 = min(i0 + 1, size - 1);
        const float valid = (coord >= 0.0f && coord <= (float)(size - 1)) ? 1.0f : 0.0f;

        if (isx) {
            xo0[i] = min(max(i0 - 1, 0), WW - 1) * CC;
            xo1[i] = min(max(i1 - 1, 0), WW - 1) * CC;
            lxv[i] = frac;
            vxv[i] = valid;
        } else {
            yo0[i] = min(max(i0 - 1, 0), HH - 1) * (WW * CC);
            yo1[i] = min(max(i1 - 1, 0), HH - 1) * (WW * CC);
            lyv[i] = frac;
            vyv[i] = valid;
        }
    }
    __syncthreads();

    // ---- pass 2: fused per-(cell,sample) weight/offset tables (t < 196) ----
    if (t < NCELL * 4) {
        const int s  = t >> 2;          // cell
        const int qq = t & 3;           // sample within cell
        const int dy = qq >> 1, dx = qq & 1;
        const int py = s / 7, px = s - py * 7;
        const int iy = 2 * py + dy, ix = 2 * px + dx;

        const float ly = lyv[iy], vy = vyv[iy];
        const float lx = lxv[ix], vx = vxv[ix];
        const float m = 0.25f * vy * vx;

        float4 w;
        w.x = m * (1.f - ly) * (1.f - lx);   // (y0,x0)
        w.y = m * (1.f - ly) * lx;           // (y0,x1)
        w.z = m * ly * (1.f - lx);           // (y1,x0)
        w.w = m * ly * lx;                   // (y1,x1)
        int4 o;
        o.x = (yo0[iy] + xo0[ix]) >> 2;      // float4-element offsets
        o.y = (yo0[iy] + xo1[ix]) >> 2;
        o.z = (yo1[iy] + xo0[ix]) >> 2;
        o.w = (yo1[iy] + xo1[ix]) >> 2;

        reinterpret_cast<float4*>(wtab)[t] = w;
        reinterpret_cast<int4*>(otab)[t]   = o;
    }
    __syncthreads();

    const int cg = t & 63;   // float4 channel group
    const int sq = t >> 6;   // wave id
    const float4* __restrict__ f4 = reinterpret_cast<const float4*>(fmap);
    const float4* wt4 = reinterpret_cast<const float4*>(wtab);
    const int4*   ot4 = reinterpret_cast<const int4*>(otab);
    const size_t base = (size_t)r * (CC * NCELL);

#pragma unroll 1
    for (int phase = 0; phase < 2; ++phase) {
        const int s_lo = phase ? PROWS : 0;
        const int s_hi = phase ? NCELL : PROWS;
        const int nrow = s_hi - s_lo;    // 25 then 24

        // ---- compute: wave pair-processes 2 cells ----
        for (int ss = s_lo + sq; ss < s_hi; ss += 8) {
            const int  s0   = ss;
            const bool has1 = (ss + 4) < s_hi;
            const int  s1   = has1 ? ss + 4 : ss;   // dup-safe
            float4 acc0 = make_float4(0.f, 0.f, 0.f, 0.f);
            float4 acc1 = make_float4(0.f, 0.f, 0.f, 0.f);
#pragma unroll
            for (int qq = 0; qq < 4; ++qq) {
                const float4 w0 = wt4[s0 * 4 + qq];
                const int4   o0 = ot4[s0 * 4 + qq];
                const float4 w1 = wt4[s1 * 4 + qq];
                const int4   o1 = ot4[s1 * 4 + qq];

                const float4 a0 = f4[o0.x + cg];
                const float4 a1 = f4[o0.y + cg];
                const float4 a2 = f4[o0.z + cg];
                const float4 a3 = f4[o0.w + cg];
                const float4 b0 = f4[o1.x + cg];
                const float4 b1 = f4[o1.y + cg];
                const float4 b2 = f4[o1.z + cg];
                const float4 b3 = f4[o1.w + cg];

                acc0.x += w0.x * a0.x + w0.y * a1.x + w0.z * a2.x + w0.w * a3.x;
                acc0.y += w0.x * a0.y + w0.y * a1.y + w0.z * a2.y + w0.w * a3.y;
                acc0.z += w0.x * a0.z + w0.y * a1.z + w0.z * a2.z + w0.w * a3.z;
                acc0.w += w0.x * a0.w + w0.y * a1.w + w0.z * a2.w + w0.w * a3.w;
                acc1.x += w1.x * b0.x + w1.y * b1.x + w1.z * b2.x + w1.w * b3.x;
                acc1.y += w1.x * b0.y + w1.y * b1.y + w1.z * b2.y + w1.w * b3.y;
                acc1.z += w1.x * b0.z + w1.y * b1.z + w1.z * b2.z + w1.w * b3.z;
                acc1.w += w1.x * b0.w + w1.y * b1.w + w1.z * b2.w + w1.w * b3.w;
            }
            // swizzled pool store: col' = c + (c>>5) -> <=2-way banks
            {
                const int row = s0 - s_lo;
                const int c0  = 4 * cg;
                const int col = c0 + (c0 >> 5);   // (4cg+j)>>5 == (4cg)>>5 for j<4
                float* d0 = &pool[row * PSTRIDE + col];
                d0[0] = acc0.x; d0[1] = acc0.y; d0[2] = acc0.z; d0[3] = acc0.w;
            }
            if (has1) {
                const int row = s1 - s_lo;
                const int c0  = 4 * cg;
                const int col = c0 + (c0 >> 5);
                float* d1 = &pool[row * PSTRIDE + col];
                d1[0] = acc1.x; d1[1] = acc1.y; d1[2] = acc1.z; d1[3] = acc1.w;
            }
        }
        __syncthreads();

        // ---- transpose write: out[r, c*49 + s] = pool[s-s_lo][c'], coalesced ----
        const int total = nrow * CC;
#pragma unroll 1
        for (int e = t; e < total; e += 256) {
            const int c  = e / nrow;
            const int sp = e - c * nrow;
            out[base + c * NCELL + s_lo + sp] = pool[sp * PSTRIDE + c + (c >> 5)];
        }
        __syncthreads();
    }
}

extern "C" void kernel_launch(void* const* d_in, const int* in_sizes, int n_in,
                              void* d_out, int out_size, void* d_ws, size_t ws_size,
                              hipStream_t stream) {
    const float* fmap = (const float*)d_in[0];
    const float* rois = (const float*)d_in[1];
    const int*   strd = (const int*)d_in[2];
    float*       out  = (float*)d_out;
    int*         perm = (int*)d_ws;
    const int n = in_sizes[1] / 4;

    roi_sort_kernel<<<1, 256, 0, stream>>>(rois, strd, n, perm);
    roi_align_kernel<<<n, 256, 0, stream>>>(fmap, rois, strd, perm, n, out);
}

// Round 11
// 215.643 us; speedup vs baseline: 1.0562x; 1.0562x over previous
//
#include <hip/hip_runtime.h>

// ROI-Align (crop_and_resize pad_border=True, 2x res + 2x2 avg pool) for
// fmap [1,200,304,256] f32, rois [N,4] f32, stride=16, out [N, 256*49] f32
// (NCHW-flattened). Symmetric pad of 1 == clamp(idx-1, 0, dim-1).
//
// R6: 89us. R10 (cell-split 2-phase): 114us REGRESSION — WRITE_SIZE 98->128MB
// (partial 64B-line overlap at the 100B/96B split of each 196B channel row).
// R11: split phases by CHANNEL halves instead:
//  - phase ph = channels [128ph,128ph+128): epilogue writes ONE contiguous
//    100KB region -> no write amplification; phases read DISJOINT cache
//    lines of each pixel -> no fetch duplication.
//  - wave = 2 cell-slots x 32 f4-channel-groups; ILP pair (s, s+8).
//  - pool tile [49][128] f32 (512B rows), f4 stores XOR-swizzled
//    (u = cg2 ^ (s&7)) -> conflict-free stores; epilogue reads ~6-way (ok).
//  - LDS ~31.8KB -> 5 blocks/CU.

#define HH 200
#define WW 304
#define CC 256
#define HP (HH + 2)
#define WP (WW + 2)
#define PS 14            // sample grid (2x resolution)
#define NCELL 49         // 7x7 pooled cells
#define HALFC 128        // channels per phase
#define NBUCKET 256      // 16x16 morton tiles

// ---------- one-block counting sort: perm[sorted_pos] = roi_idx ----------
__global__ __launch_bounds__(256) void roi_sort_kernel(
    const float* __restrict__ rois,
    const int*   __restrict__ stride_p,
    int n, int* __restrict__ perm)
{
    __shared__ int hist[NBUCKET];
    __shared__ int scan[NBUCKET];
    __shared__ int offs[NBUCKET];
    const int t = threadIdx.x;
    hist[t] = 0;
    __syncthreads();

    const float inv = 1.0f / (float)stride_p[0];
    auto key_of = [&](int i) -> int {
        const float cx = 0.5f * (rois[4 * i + 0] + rois[4 * i + 2]) * inv;
        const float cy = 0.5f * (rois[4 * i + 1] + rois[4 * i + 3]) * inv;
        int tx = (int)(cx * (16.0f / (float)WW));
        int ty = (int)(cy * (16.0f / (float)HH));
        tx = min(max(tx, 0), 15);
        ty = min(max(ty, 0), 15);
        int k = 0;
#pragma unroll
        for (int b = 0; b < 4; ++b)
            k |= (((tx >> b) & 1) << (2 * b)) | (((ty >> b) & 1) << (2 * b + 1));
        return k;
    };

    for (int i = t; i < n; i += 256) atomicAdd(&hist[key_of(i)], 1);
    __syncthreads();

    scan[t] = hist[t];
    __syncthreads();
    for (int d = 1; d < NBUCKET; d <<= 1) {
        const int x = (t >= d) ? scan[t - d] : 0;
        __syncthreads();
        scan[t] += x;
        __syncthreads();
    }
    offs[t] = scan[t] - hist[t];   // exclusive
    __syncthreads();

    for (int i = t; i < n; i += 256) {
        const int pos = atomicAdd(&offs[key_of(i)], 1);
        perm[pos] = i;
    }
}

// ---------- main kernel ----------
__global__ __launch_bounds__(256, 5) void roi_align_kernel(
    const float* __restrict__ fmap,
    const float* __restrict__ rois,
    const int*   __restrict__ stride_p,
    const int*   __restrict__ perm,
    int nwg,
    float*       __restrict__ out)
{
    __shared__ alignas(16) float pool[NCELL * HALFC];   // 25.1 KB, 512B rows
    __shared__ alignas(16) float wtab[NCELL * 16];      // 3.1 KB: [s][q][4] weights
    __shared__ alignas(16) int   otab[NCELL * 16];      // 3.1 KB: [s][q][4] f4-offsets
    __shared__ int   yo0[PS], yo1[PS], xo0[PS], xo1[PS];
    __shared__ float lyv[PS], vyv[PS], lxv[PS], vxv[PS];

    const int t = threadIdx.x;

    // bijective XCD-chunk swizzle: XCD k gets a contiguous sorted range
    const int bid = blockIdx.x;
    const int q8 = nwg >> 3, rem = nwg & 7;
    const int xcd = bid & 7, idx8 = bid >> 3;
    const int swz = (xcd < rem ? xcd * (q8 + 1) : rem * (q8 + 1) + (xcd - rem) * q8) + idx8;
    const int r = perm[swz];

    // ---- pass 1: separable index/weight tables (threads 0..27) ----
    if (t < 2 * PS) {
        const bool isx = (t >= PS);
        const int  i   = isx ? (t - PS) : t;
        const float inv = 1.0f / (float)stride_p[0];
        const float a0 = rois[4 * r + (isx ? 0 : 1)] * inv + 1.0f;
        const float a1 = rois[4 * r + (isx ? 2 : 3)] * inv + 1.0f;
        const float sc = (a1 - a0) / (float)PS;
        const float coord = a0 + sc * ((float)i + 0.5f) - 0.5f;
        const int size = isx ? WP : HP;

        const float f0   = floorf(coord);
        const float frac = coord - f0;
        int i0 = (int)f0;
        i0 = min(max(i0, 0), size - 1);
        const int i1 = min(i0 + 1, size - 1);
        const float valid = (coord >= 0.0f && coord <= (float)(size - 1)) ? 1.0f : 0.0f;

        if (isx) {
            xo0[i] = min(max(i0 - 1, 0), WW - 1) * CC;
            xo1[i] = min(max(i1 - 1, 0), WW - 1) * CC;
            lxv[i] = frac;
            vxv[i] = valid;
        } else {
            yo0[i] = min(max(i0 - 1, 0), HH - 1) * (WW * CC);
            yo1[i] = min(max(i1 - 1, 0), HH - 1) * (WW * CC);
            lyv[i] = frac;
            vyv[i] = valid;
        }
    }
    __syncthreads();

    // ---- pass 2: fused per-(cell,sample) weight/offset tables (t < 196) ----
    if (t < NCELL * 4) {
        const int s  = t >> 2;          // cell
        const int qq = t & 3;           // sample within cell
        const int dy = qq >> 1, dx = qq & 1;
        const int py = s / 7, px = s - py * 7;
        const int iy = 2 * py + dy, ix = 2 * px + dx;

        const float ly = lyv[iy], vy = vyv[iy];
        const float lx = lxv[ix], vx = vxv[ix];
        const float m = 0.25f * vy * vx;

        float4 w;
        w.x = m * (1.f - ly) * (1.f - lx);   // (y0,x0)
        w.y = m * (1.f - ly) * lx;           // (y0,x1)
        w.z = m * ly * (1.f - lx);           // (y1,x0)
        w.w = m * ly * lx;                   // (y1,x1)
        int4 o;
        o.x = (yo0[iy] + xo0[ix]) >> 2;      // float4-element offsets
        o.y = (yo0[iy] + xo1[ix]) >> 2;
        o.z = (yo1[iy] + xo0[ix]) >> 2;
        o.w = (yo1[iy] + xo1[ix]) >> 2;

        reinterpret_cast<float4*>(wtab)[t] = w;
        reinterpret_cast<int4*>(otab)[t]   = o;
    }
    __syncthreads();

    const int slot = t >> 5;     // 0..7: cell slot (wave*2 + half)
    const int cg2  = t & 31;     // f4 channel-group within the 128-ch half
    const float4* __restrict__ f4 = reinterpret_cast<const float4*>(fmap);
    const float4* wt4 = reinterpret_cast<const float4*>(wtab);
    const int4*   ot4 = reinterpret_cast<const int4*>(otab);
    float4* pool4 = reinterpret_cast<float4*>(pool);
    const size_t base = (size_t)r * (CC * NCELL);

#pragma unroll 1
    for (int ph = 0; ph < 2; ++ph) {
        const int phbase = ph * 32 + cg2;   // f4 offset within pixel

        // ---- compute: slot handles cells {slot, slot+8, ...}, ILP pair (s, s+8) ----
        for (int s = slot; s < NCELL; s += 16) {
            const bool has1 = (s + 8) < NCELL;
            const int  s1   = has1 ? s + 8 : s;
            float4 acc0 = make_float4(0.f, 0.f, 0.f, 0.f);
            float4 acc1 = make_float4(0.f, 0.f, 0.f, 0.f);
#pragma unroll
            for (int qq = 0; qq < 4; ++qq) {
                const float4 w0 = wt4[s * 4 + qq];
                const int4   o0 = ot4[s * 4 + qq];
                const float4 w1 = wt4[s1 * 4 + qq];
                const int4   o1 = ot4[s1 * 4 + qq];

                const float4 a0 = f4[o0.x + phbase];
                const float4 a1 = f4[o0.y + phbase];
                const float4 a2 = f4[o0.z + phbase];
                const float4 a3 = f4[o0.w + phbase];
                const float4 b0 = f4[o1.x + phbase];
                const float4 b1 = f4[o1.y + phbase];
                const float4 b2 = f4[o1.z + phbase];
                const float4 b3 = f4[o1.w + phbase];

                acc0.x += w0.x * a0.x + w0.y * a1.x + w0.z * a2.x + w0.w * a3.x;
                acc0.y += w0.x * a0.y + w0.y * a1.y + w0.z * a2.y + w0.w * a3.y;
                acc0.z += w0.x * a0.z + w0.y * a1.z + w0.z * a2.z + w0.w * a3.z;
                acc0.w += w0.x * a0.w + w0.y * a1.w + w0.z * a2.w + w0.w * a3.w;
                acc1.x += w1.x * b0.x + w1.y * b1.x + w1.z * b2.x + w1.w * b3.x;
                acc1.y += w1.x * b0.y + w1.y * b1.y + w1.z * b2.y + w1.w * b3.y;
                acc1.z += w1.x * b0.z + w1.y * b1.z + w1.z * b2.z + w1.w * b3.z;
                acc1.w += w1.x * b0.w + w1.y * b1.w + w1.z * b2.w + w1.w * b3.w;
            }
            // f4 store, XOR-swizzled 16B unit: row s, unit cg2^(s&7)
            pool4[s * 32 + (cg2 ^ (s & 7))] = acc0;
            if (has1)
                pool4[s1 * 32 + (cg2 ^ (s1 & 7))] = acc1;
        }
        __syncthreads();

        // ---- epilogue: out[base + (128ph+c)*49 + s] — one contiguous 100KB streak ----
#pragma unroll 1
        for (int e = t; e < NCELL * HALFC; e += 256) {
            const int c_loc = e / NCELL;            // 0..127
            const int sp    = e - c_loc * NCELL;    // 0..48
            const int u     = (c_loc >> 2) ^ (sp & 7);
            const float v   = pool[sp * HALFC + (u << 2) + (c_loc & 3)];
            out[base + (size_t)(ph * HALFC + c_loc) * NCELL + sp] = v;
        }
        __syncthreads();
    }
}

extern "C" void kernel_launch(void* const* d_in, const int* in_sizes, int n_in,
                              void* d_out, int out_size, void* d_ws, size_t ws_size,
                              hipStream_t stream) {
    const float* fmap = (const float*)d_in[0];
    const float* rois = (const float*)d_in[1];
    const int*   strd = (const int*)d_in[2];
    float*       out  = (float*)d_out;
    int*         perm = (int*)d_ws;
    const int n = in_sizes[1] / 4;

    roi_sort_kernel<<<1, 256, 0, stream>>>(rois, strd, n, perm);
    roi_align_kernel<<<n, 256, 0, stream>>>(fmap, rois, strd, perm, n, out);
}